// Round 10
// baseline (247.837 us; speedup 1.0000x reference)
//
#include <hip/hip_runtime.h>

// Problem constants (B=4, C=256, H=W=64 -> T=4096)
constexpr int kB  = 4;
constexpr int kC  = 256;
constexpr int kT  = 4096;
constexpr int kG  = 16;
constexpr int kCg = kC / kG;   // 16 channels per group
constexpr int kH  = 4;         // heads
constexpr int kCh = kC / kH;   // 64 channels per head
constexpr float kEps = 1e-5f;
// q scale: 1/8 (=scale^2) folded with log2(e) for exp2-domain softmax
constexpr float kQScale = 0.125f * 1.4426950408889634f;

typedef short bf16x8 __attribute__((ext_vector_type(8)));
typedef float f32x4  __attribute__((ext_vector_type(4)));
typedef float f32x16 __attribute__((ext_vector_type(16)));

__device__ inline unsigned short f2bf(float f) {
    union { float f; unsigned u; } v; v.f = f;
    unsigned r = v.u + 0x7fffu + ((v.u >> 16) & 1u);   // RNE
    return (unsigned short)(r >> 16);
}
__device__ inline unsigned pk2bf(float a, float b) {
    return (unsigned)f2bf(a) | ((unsigned)f2bf(b) << 16);
}
// truncating pack of two fp32 -> bf16x2 in ONE v_perm_b32 (high halves)
__device__ inline unsigned pk2bf_trunc(float a, float b) {
    return __builtin_amdgcn_perm(__float_as_uint(b), __float_as_uint(a), 0x07060302u);
}

// ---------------------------------------------------------------------------
// Kernel 1: GroupNorm statistics (blocks 0..63) + weight fp32->bf16 convert
// (blocks 64..191) fused into one launch.
// ---------------------------------------------------------------------------
__global__ __launch_bounds__(256) void prep_kernel(const float* __restrict__ x,
                                                   float* __restrict__ stats,
                                                   const float* __restrict__ qkv_w,
                                                   const float* __restrict__ proj_w,
                                                   unsigned short* __restrict__ wbf) {
    int tid = threadIdx.x;
    if (blockIdx.x >= 64) {
        int gid = (blockIdx.x - 64) * 256 + tid;
        for (int i = gid; i < 65536; i += 128 * 256) {
            float4 v = (i < 49152) ? ((const float4*)qkv_w)[i]
                                   : ((const float4*)proj_w)[i - 49152];
            *(uint2*)&wbf[(size_t)i * 4] = make_uint2(pk2bf(v.x, v.y), pk2bf(v.z, v.w));
        }
        return;
    }
    int bg = blockIdx.x;
    const float4* xp4 = (const float4*)(x + (size_t)bg * (kCg * kT));
    float s = 0.f, q = 0.f;
    #pragma unroll 4
    for (int i = 0; i < (kCg * kT / 4) / 256; ++i) {
        float4 v = xp4[tid + i * 256];
        s += v.x + v.y + v.z + v.w;
        q += v.x * v.x + v.y * v.y + v.z * v.z + v.w * v.w;
    }
    #pragma unroll
    for (int off = 32; off > 0; off >>= 1) {
        s += __shfl_down(s, off);
        q += __shfl_down(q, off);
    }
    __shared__ float rs[4], rq[4];
    int wid = tid >> 6, lane = tid & 63;
    if (lane == 0) { rs[wid] = s; rq[wid] = q; }
    __syncthreads();
    if (tid == 0) {
        float S = rs[0] + rs[1] + rs[2] + rs[3];
        float Q = rq[0] + rq[1] + rq[2] + rq[3];
        const float invN = 1.0f / (float)(kCg * kT);
        float mean = S * invN;
        float var  = Q * invN - mean * mean;
        stats[bg * 2 + 0] = mean;
        stats[bg * 2 + 1] = rsqrtf(var + kEps);
    }
}

// ---------------------------------------------------------------------------
// Kernel 2: apply GroupNorm affine + transpose -> normT[b][t][c] bf16.
// ---------------------------------------------------------------------------
__global__ __launch_bounds__(256) void gn_apply_t_kernel(const float* __restrict__ x,
                                                         const float* __restrict__ stats,
                                                         const float* __restrict__ w,
                                                         const float* __restrict__ bias,
                                                         unsigned short* __restrict__ normT) {
    __shared__ float Ls[64][65];
    int t0 = blockIdx.x * 64;
    int c0 = blockIdx.y * 64;
    int b  = blockIdx.z;
    int tid = threadIdx.x;
    #pragma unroll
    for (int p = 0; p < 4; ++p) {
        int idx = tid + p * 256;
        int cl = idx >> 4, t4 = idx & 15;
        int c = c0 + cl;
        int bg = b * kG + (c >> 4);
        float mean = stats[bg * 2 + 0];
        float rstd = stats[bg * 2 + 1];
        float sw = w[c] * rstd;
        float sb = bias[c] - mean * sw;
        float4 v = *(const float4*)&x[((size_t)b * kC + c) * kT + t0 + t4 * 4];
        Ls[t4 * 4 + 0][cl] = v.x * sw + sb;
        Ls[t4 * 4 + 1][cl] = v.y * sw + sb;
        Ls[t4 * 4 + 2][cl] = v.z * sw + sb;
        Ls[t4 * 4 + 3][cl] = v.w * sw + sb;
    }
    __syncthreads();
    {
        int row = tid >> 2, cq = (tid & 3) * 16;
        unsigned tmp[8];
        #pragma unroll
        for (int i = 0; i < 8; ++i)
            tmp[i] = pk2bf(Ls[row][cq + 2 * i], Ls[row][cq + 2 * i + 1]);
        uint4* dst = (uint4*)&normT[((size_t)b * kT + t0 + row) * kC + c0 + cq];
        dst[0] = make_uint4(tmp[0], tmp[1], tmp[2], tmp[3]);
        dst[1] = make_uint4(tmp[4], tmp[5], tmp[6], tmp[7]);
    }
}

// ---------------------------------------------------------------------------
// Kernel 3: qkv GEMM (bf16 MFMA) with register prefetch of the next K-tile
// (global loads issued right after staging barrier, complete during MFMAs).
// Epilogue writes q/k/v in PRE-FRAGMENTED MFMA operand layouts:
//   q/k: frag[tb=t/32][ks=c/16][hi=(c/8)&1][ln=t&31][e=c&7]
//   v:   frag[sg=s/16][hi=(s/8)&1][c][e=s&7]
// ---------------------------------------------------------------------------
__global__ __launch_bounds__(256) void qkv_gemm_kernel(const unsigned short* __restrict__ wbf,
                                                       const float* __restrict__ qkv_b,
                                                       const unsigned short* __restrict__ normT,
                                                       unsigned short* __restrict__ qTg,
                                                       unsigned short* __restrict__ kTg,
                                                       unsigned short* __restrict__ vCg) {
    constexpr int LDK = 72;
    constexpr int LDV = 136;   // v-staging row length (bf16), 272 B, 16B-aligned
    __shared__ __align__(16) unsigned short As[64 * LDK];
    __shared__ __align__(16) unsigned short Bs[128 * LDK];   // also epilogue staging

    int t0 = blockIdx.x * 128;
    int m0 = blockIdx.y * 64;
    int b  = blockIdx.z;
    const unsigned short* Ab = wbf + (size_t)m0 * kC;
    const unsigned short* Bb = normT + (size_t)b * kT * kC;

    int tid = threadIdx.x;
    int wave = tid >> 6, lane = tid & 63;
    int ln15 = lane & 15, quad = lane >> 4;
    int wm = wave >> 1, wt = wave & 1;

    int arow = tid >> 3, aseg = tid & 7;   // A: 2 chunks (rows 0..63 via +32)
    f32x4 acc[2][4] = {};
    uint4 Ar[2], Br[4];

    // prologue: load K-tile 0 into registers
    #pragma unroll
    for (int p = 0; p < 2; ++p)
        Ar[p] = *(const uint4*)&Ab[(size_t)(arow + p * 32) * kC + aseg * 8];
    #pragma unroll
    for (int p = 0; p < 4; ++p)
        Br[p] = *(const uint4*)&Bb[(size_t)(t0 + arow + p * 32) * kC + aseg * 8];

    for (int k0 = 0; k0 < kC; k0 += 64) {
        if (k0) __syncthreads();   // prev MFMA reads done before overwrite
        #pragma unroll
        for (int p = 0; p < 2; ++p)
            *(uint4*)&As[(arow + p * 32) * LDK + aseg * 8] = Ar[p];
        #pragma unroll
        for (int p = 0; p < 4; ++p)
            *(uint4*)&Bs[(arow + p * 32) * LDK + aseg * 8] = Br[p];
        __syncthreads();
        if (k0 + 64 < kC) {   // prefetch next K-tile (hidden behind MFMAs)
            #pragma unroll
            for (int p = 0; p < 2; ++p)
                Ar[p] = *(const uint4*)&Ab[(size_t)(arow + p * 32) * kC + k0 + 64 + aseg * 8];
            #pragma unroll
            for (int p = 0; p < 4; ++p)
                Br[p] = *(const uint4*)&Bb[(size_t)(t0 + arow + p * 32) * kC + k0 + 64 + aseg * 8];
        }
        #pragma unroll
        for (int ks = 0; ks < 2; ++ks) {
            bf16x8 af[2], bf[4];
            #pragma unroll
            for (int i = 0; i < 2; ++i)
                af[i] = *(bf16x8*)&As[(wm * 32 + i * 16 + ln15) * LDK + ks * 32 + quad * 8];
            #pragma unroll
            for (int j = 0; j < 4; ++j)
                bf[j] = *(bf16x8*)&Bs[(wt * 64 + j * 16 + ln15) * LDK + ks * 32 + quad * 8];
            #pragma unroll
            for (int i = 0; i < 2; ++i)
                #pragma unroll
                for (int j = 0; j < 4; ++j)
                    acc[i][j] = __builtin_amdgcn_mfma_f32_16x16x32_bf16(
                        af[i], bf[j], acc[i][j], 0, 0, 0);
        }
    }

    int type = (m0 % 192) / 64;   // 0=q, 1=k, 2=v
    int h = m0 / 192;
    int bh = b * kH + h;
    __syncthreads();   // all MFMA reads of Bs done; reuse Bs as staging
    #pragma unroll
    for (int i = 0; i < 2; ++i) {
        float4 bv = *(const float4*)&qkv_b[m0 + wm * 32 + i * 16 + quad * 4];
        const float* bp = (const float*)&bv;
        #pragma unroll
        for (int j = 0; j < 4; ++j) {
            int tl = wt * 64 + j * 16 + ln15;
            int c = wm * 32 + i * 16 + quad * 4;
            float v0 = acc[i][j][0] + bp[0];
            float v1 = acc[i][j][1] + bp[1];
            float v2 = acc[i][j][2] + bp[2];
            float v3 = acc[i][j][3] + bp[3];
            if (type == 0) {
                v0 *= kQScale; v1 *= kQScale; v2 *= kQScale; v3 *= kQScale;
            }
            if (type != 2) {
                *(uint2*)&Bs[tl * LDK + c] = make_uint2(pk2bf(v0, v1), pk2bf(v2, v3));
            } else {
                Bs[(c + 0) * LDV + tl] = f2bf(v0);
                Bs[(c + 1) * LDV + tl] = f2bf(v1);
                Bs[(c + 2) * LDV + tl] = f2bf(v2);
                Bs[(c + 3) * LDV + tl] = f2bf(v3);
            }
        }
    }
    __syncthreads();
    if (type != 2) {
        unsigned short* base = ((type == 0) ? qTg : kTg) + (size_t)bh * (kT * kCh);
        #pragma unroll
        for (int p = 0; p < 4; ++p) {
            int f = tid + p * 256;
            int ln = f & 31, hif = (f >> 5) & 1, ks = (f >> 6) & 3, tb = f >> 8;
            *(uint4*)&base[((t0 >> 5) + tb) * 2048 + ks * 512 + hif * 256 + ln * 8] =
                *(uint4*)&Bs[(tb * 32 + ln) * LDK + ks * 16 + hif * 8];
        }
    } else {
        unsigned short* base = vCg + (size_t)bh * (kT * kCh);
        #pragma unroll
        for (int p = 0; p < 4; ++p) {
            int f = tid + p * 256;
            int c = f & 63, hif = (f >> 6) & 1, sg = f >> 7;
            *(uint4*)&base[((t0 >> 4) + sg) * 1024 + hif * 512 + c * 8] =
                *(uint4*)&Bs[c * LDV + sg * 16 + hif * 8];
        }
    }
}

// ---------------------------------------------------------------------------
// Kernel 4: MFMA flash attention, 32x32x16, no-max exp2 softmax.
// s-step 128 per barrier pair: two independent 64-s subtiles per iteration
// (8 S-MFMAs + 32 exp2 + 8 O-MFMAs between barriers; softmax of subtile 0
// overlaps matrix-pipe execution of subtile 1). Q/K/V fragments in
// registers from pre-fragmented global layouts, prefetched one iteration
// ahead. Only P transits LDS; two barriers/iter (proven-safe protocol).
// C/D layout: col=lane&31, row=(reg&3)+8*(reg>>2)+4*hi (m74/m101).
// ---------------------------------------------------------------------------
__global__ __launch_bounds__(256, 3) void attn_mfma_kernel(const unsigned short* __restrict__ qTg,
                                                           const unsigned short* __restrict__ kTg,
                                                           const unsigned short* __restrict__ vCg,
                                                           unsigned short* __restrict__ attnT) {
    constexpr int LDP = 136;   // P row length (bf16): 128 s + 8 pad, 272 B
    __shared__ __align__(16) unsigned short Ps[64 * LDP];
    __shared__ float l_part[2][64];

    int bh = blockIdx.y;
    int t0 = blockIdx.x * 64;
    int b = bh >> 2, h = bh & 3;

    int tid = threadIdx.x;
    int wave = tid >> 6, lane = tid & 63;
    int ln31 = lane & 31, hi = lane >> 5;
    int sh = wave >> 1, th = wave & 1;

    const unsigned short* qb = qTg + (size_t)bh * (kT * kCh);
    const unsigned short* kb = kTg + (size_t)bh * (kT * kCh);
    const unsigned short* vb = vCg + (size_t)bh * (kT * kCh);

    // Q fragments (loop-invariant)
    bf16x8 qf[4];
    {
        const unsigned short* qp = qb + ((t0 >> 5) + th) * 2048 + hi * 256 + ln31 * 8;
        #pragma unroll
        for (int ks = 0; ks < 4; ++ks) qf[ks] = *(const bf16x8*)(qp + ks * 512);
    }
    // K/V fragment pointers (advance 8192 elems per 128-s iteration)
    const unsigned short* kptr = kb + sh * 2048 + hi * 256 + ln31 * 8;
    const unsigned short* vptr = vb + hi * 512 + (sh * 32 + ln31) * 8;

    bf16x8 kf[8], vf[8];
    #pragma unroll
    for (int i = 0; i < 8; ++i)
        kf[i] = *(const bf16x8*)(kptr + (i >> 2) * 4096 + (i & 3) * 512);
    #pragma unroll
    for (int i = 0; i < 8; ++i)
        vf[i] = *(const bf16x8*)(vptr + i * 1024);

    float l_r = 0.f;
    f32x16 accO = {};

    for (int s0 = 0; s0 < kT; s0 += 128) {
        // ---- S^T: two independent 64-s subtiles (8 MFMAs)
        f32x16 accS0 = {}, accS1 = {};
        #pragma unroll
        for (int ks = 0; ks < 4; ++ks)
            accS0 = __builtin_amdgcn_mfma_f32_32x32x16_bf16(kf[ks], qf[ks], accS0, 0, 0, 0);
        #pragma unroll
        for (int ks = 0; ks < 4; ++ks)
            accS1 = __builtin_amdgcn_mfma_f32_32x32x16_bf16(kf[4 + ks], qf[ks], accS1, 0, 0, 0);

        // prefetch next K fragments
        if (s0 + 128 < kT) {
            kptr += 8192;
            #pragma unroll
            for (int i = 0; i < 8; ++i)
                kf[i] = *(const bf16x8*)(kptr + (i >> 2) * 4096 + (i & 3) * 512);
        }

        // ---- no-max softmax: p = exp2(S); lane owns col t = th*32+ln31
        int t = th * 32 + ln31;
        float rs = 0.f;
        #pragma unroll
        for (int g = 0; g < 4; ++g) {
            float p0 = __builtin_amdgcn_exp2f(accS0[4 * g + 0]);
            float p1 = __builtin_amdgcn_exp2f(accS0[4 * g + 1]);
            float p2 = __builtin_amdgcn_exp2f(accS0[4 * g + 2]);
            float p3 = __builtin_amdgcn_exp2f(accS0[4 * g + 3]);
            rs += (p0 + p1) + (p2 + p3);
            *(uint2*)&Ps[t * LDP + sh * 32 + 8 * g + 4 * hi] =
                make_uint2(pk2bf_trunc(p0, p1), pk2bf_trunc(p2, p3));
        }
        #pragma unroll
        for (int g = 0; g < 4; ++g) {
            float p0 = __builtin_amdgcn_exp2f(accS1[4 * g + 0]);
            float p1 = __builtin_amdgcn_exp2f(accS1[4 * g + 1]);
            float p2 = __builtin_amdgcn_exp2f(accS1[4 * g + 2]);
            float p3 = __builtin_amdgcn_exp2f(accS1[4 * g + 3]);
            rs += (p0 + p1) + (p2 + p3);
            *(uint2*)&Ps[t * LDP + 64 + sh * 32 + 8 * g + 4 * hi] =
                make_uint2(pk2bf_trunc(p0, p1), pk2bf_trunc(p2, p3));
        }
        rs += __shfl_xor(rs, 32);
        l_r += rs;
        __syncthreads();   // barrier 1: P complete before any wave reads

        // ---- O^T: over s=128 (8 MFMAs)
        #pragma unroll
        for (int i = 0; i < 8; ++i) {
            bf16x8 pf = *(bf16x8*)&Ps[(th * 32 + ln31) * LDP + i * 16 + hi * 8];
            accO = __builtin_amdgcn_mfma_f32_32x32x16_bf16(vf[i], pf, accO, 0, 0, 0);
        }

        // prefetch next V fragments
        if (s0 + 128 < kT) {
            vptr += 8192;
            #pragma unroll
            for (int i = 0; i < 8; ++i)
                vf[i] = *(const bf16x8*)(vptr + i * 1024);
        }
        __syncthreads();   // barrier 2: all P reads done before next writes
    }

    // combine l partials across the two s-half waves
    if (hi == 0) l_part[sh][th * 32 + ln31] = l_r;
    __syncthreads();
    int t = th * 32 + ln31;
    float linv = 1.0f / (l_part[0][t] + l_part[1][t]);
    #pragma unroll
    for (int g = 0; g < 4; ++g) {
        int c = sh * 32 + 8 * g + 4 * hi;   // + (0..3) from reg&3
        float v0 = accO[4 * g + 0] * linv;
        float v1 = accO[4 * g + 1] * linv;
        float v2 = accO[4 * g + 2] * linv;
        float v3 = accO[4 * g + 3] * linv;
        *(uint2*)&attnT[((size_t)b * kT + t0 + t) * kC + h * kCh + c] =
            make_uint2(pk2bf(v0, v1), pk2bf(v2, v3));
    }
}

// ---------------------------------------------------------------------------
// Kernel 5: proj GEMM (bf16 MFMA, register prefetch) + bias + residual.
// ---------------------------------------------------------------------------
__global__ __launch_bounds__(256) void proj_gemm_kernel(const unsigned short* __restrict__ wpbf,
                                                        const float* __restrict__ proj_b,
                                                        const unsigned short* __restrict__ attnT,
                                                        const float* __restrict__ x,
                                                        float* __restrict__ out) {
    constexpr int LDK = 72;
    __shared__ __align__(16) unsigned short As[64 * LDK];
    __shared__ __align__(16) unsigned short Bs[128 * LDK];

    int t0 = blockIdx.x * 128;
    int m0 = blockIdx.y * 64;
    int b  = blockIdx.z;
    const unsigned short* Ab = wpbf + (size_t)m0 * kC;
    const unsigned short* Bb = attnT + (size_t)b * kT * kC;

    int tid = threadIdx.x;
    int wave = tid >> 6, lane = tid & 63;
    int ln15 = lane & 15, quad = lane >> 4;
    int wm = wave >> 1, wt = wave & 1;

    int arow = tid >> 3, aseg = tid & 7;
    f32x4 acc[2][4] = {};
    uint4 Ar[2], Br[4];

    #pragma unroll
    for (int p = 0; p < 2; ++p)
        Ar[p] = *(const uint4*)&Ab[(size_t)(arow + p * 32) * kC + aseg * 8];
    #pragma unroll
    for (int p = 0; p < 4; ++p)
        Br[p] = *(const uint4*)&Bb[(size_t)(t0 + arow + p * 32) * kC + aseg * 8];

    for (int k0 = 0; k0 < kC; k0 += 64) {
        if (k0) __syncthreads();
        #pragma unroll
        for (int p = 0; p < 2; ++p)
            *(uint4*)&As[(arow + p * 32) * LDK + aseg * 8] = Ar[p];
        #pragma unroll
        for (int p = 0; p < 4; ++p)
            *(uint4*)&Bs[(arow + p * 32) * LDK + aseg * 8] = Br[p];
        __syncthreads();
        if (k0 + 64 < kC) {
            #pragma unroll
            for (int p = 0; p < 2; ++p)
                Ar[p] = *(const uint4*)&Ab[(size_t)(arow + p * 32) * kC + k0 + 64 + aseg * 8];
            #pragma unroll
            for (int p = 0; p < 4; ++p)
                Br[p] = *(const uint4*)&Bb[(size_t)(t0 + arow + p * 32) * kC + k0 + 64 + aseg * 8];
        }
        #pragma unroll
        for (int ks = 0; ks < 2; ++ks) {
            bf16x8 af[2], bf[4];
            #pragma unroll
            for (int i = 0; i < 2; ++i)
                af[i] = *(bf16x8*)&As[(wm * 32 + i * 16 + ln15) * LDK + ks * 32 + quad * 8];
            #pragma unroll
            for (int j = 0; j < 4; ++j)
                bf[j] = *(bf16x8*)&Bs[(wt * 64 + j * 16 + ln15) * LDK + ks * 32 + quad * 8];
            #pragma unroll
            for (int i = 0; i < 2; ++i)
                #pragma unroll
                for (int j = 0; j < 4; ++j)
                    acc[i][j] = __builtin_amdgcn_mfma_f32_16x16x32_bf16(
                        af[i], bf[j], acc[i][j], 0, 0, 0);
        }
    }

    #pragma unroll
    for (int i = 0; i < 2; ++i) {
        float4 bv = *(const float4*)&proj_b[m0 + wm * 32 + i * 16 + quad * 4];
        const float* bp = (const float*)&bv;
        #pragma unroll
        for (int j = 0; j < 4; ++j) {
            int t = t0 + wt * 64 + j * 16 + ln15;
            int mbase = m0 + wm * 32 + i * 16 + quad * 4;
            #pragma unroll
            for (int r = 0; r < 4; ++r) {
                size_t off = ((size_t)b * kC + mbase + r) * kT + t;
                out[off] = acc[i][j][r] + bp[r] + x[off];
            }
        }
    }
}

// ---------------------------------------------------------------------------
extern "C" void kernel_launch(void* const* d_in, const int* in_sizes, int n_in,
                              void* d_out, int out_size, void* d_ws, size_t ws_size,
                              hipStream_t stream) {
    const float* x      = (const float*)d_in[0];
    const float* norm_w = (const float*)d_in[1];
    const float* norm_b = (const float*)d_in[2];
    const float* qkv_w  = (const float*)d_in[3];
    const float* qkv_b  = (const float*)d_in[4];
    const float* proj_w = (const float*)d_in[5];
    const float* proj_b = (const float*)d_in[6];
    float* out = (float*)d_out;

    // Workspace: stats fp32[128] | bf16: normT[4.19M] wbf[262144] qT kT vC attnT[4.19M each]
    float* stats = (float*)d_ws;
    unsigned short* wsbf  = (unsigned short*)((float*)d_ws + 128);
    unsigned short* normT = wsbf;
    unsigned short* wbf   = normT + (size_t)kB * kT * kC;
    unsigned short* qTp   = wbf + 262144;
    unsigned short* kTp   = qTp + (size_t)kB * kH * kT * kCh;
    unsigned short* vCp   = kTp + (size_t)kB * kH * kT * kCh;
    unsigned short* attnT = vCp + (size_t)kB * kH * kT * kCh;
    unsigned short* wpbf  = wbf + 196608;

    prep_kernel<<<192, 256, 0, stream>>>(x, stats, qkv_w, proj_w, wbf);
    gn_apply_t_kernel<<<dim3(kT / 64, kC / 64, kB), 256, 0, stream>>>(
        x, stats, norm_w, norm_b, normT);
    qkv_gemm_kernel<<<dim3(kT / 128, 12, kB), 256, 0, stream>>>(
        wbf, qkv_b, normT, qTp, kTp, vCp);
    attn_mfma_kernel<<<dim3(kT / 64, kB * kH), 256, 0, stream>>>(qTp, kTp, vCp, attnT);
    proj_gemm_kernel<<<dim3(kT / 128, kC / 64, kB), 256, 0, stream>>>(
        wpbf, proj_b, attnT, x, out);
}

// Round 13
// 215.737 us; speedup vs baseline: 1.1488x; 1.1488x over previous
//
#include <hip/hip_runtime.h>

// Problem constants (B=4, C=256, H=W=64 -> T=4096)
constexpr int kB  = 4;
constexpr int kC  = 256;
constexpr int kT  = 4096;
constexpr int kG  = 16;
constexpr int kCg = kC / kG;   // 16 channels per group
constexpr int kH  = 4;         // heads
constexpr int kCh = kC / kH;   // 64 channels per head
constexpr float kEps = 1e-5f;
// q scale: 1/8 (=scale^2) folded with log2(e) for exp2-domain softmax
constexpr float kQScale = 0.125f * 1.4426950408889634f;

typedef short bf16x8 __attribute__((ext_vector_type(8)));
typedef float f32x4  __attribute__((ext_vector_type(4)));
typedef float f32x16 __attribute__((ext_vector_type(16)));

__device__ inline unsigned short f2bf(float f) {
    union { float f; unsigned u; } v; v.f = f;
    unsigned r = v.u + 0x7fffu + ((v.u >> 16) & 1u);   // RNE
    return (unsigned short)(r >> 16);
}
__device__ inline unsigned pk2bf(float a, float b) {
    return (unsigned)f2bf(a) | ((unsigned)f2bf(b) << 16);
}
// truncating pack of two fp32 -> bf16x2 in ONE v_perm_b32 (high halves)
__device__ inline unsigned pk2bf_trunc(float a, float b) {
    return __builtin_amdgcn_perm(__float_as_uint(b), __float_as_uint(a), 0x07060302u);
}

// ---------------------------------------------------------------------------
// Kernel 1: GroupNorm statistics (blocks 0..63) + weight fp32->bf16 convert
// (blocks 64..191) fused into one launch.
// ---------------------------------------------------------------------------
__global__ __launch_bounds__(256) void prep_kernel(const float* __restrict__ x,
                                                   float* __restrict__ stats,
                                                   const float* __restrict__ qkv_w,
                                                   const float* __restrict__ proj_w,
                                                   unsigned short* __restrict__ wbf) {
    int tid = threadIdx.x;
    if (blockIdx.x >= 64) {
        int gid = (blockIdx.x - 64) * 256 + tid;
        for (int i = gid; i < 65536; i += 128 * 256) {
            float4 v = (i < 49152) ? ((const float4*)qkv_w)[i]
                                   : ((const float4*)proj_w)[i - 49152];
            *(uint2*)&wbf[(size_t)i * 4] = make_uint2(pk2bf(v.x, v.y), pk2bf(v.z, v.w));
        }
        return;
    }
    int bg = blockIdx.x;
    const float4* xp4 = (const float4*)(x + (size_t)bg * (kCg * kT));
    float s = 0.f, q = 0.f;
    #pragma unroll 4
    for (int i = 0; i < (kCg * kT / 4) / 256; ++i) {
        float4 v = xp4[tid + i * 256];
        s += v.x + v.y + v.z + v.w;
        q += v.x * v.x + v.y * v.y + v.z * v.z + v.w * v.w;
    }
    #pragma unroll
    for (int off = 32; off > 0; off >>= 1) {
        s += __shfl_down(s, off);
        q += __shfl_down(q, off);
    }
    __shared__ float rs[4], rq[4];
    int wid = tid >> 6, lane = tid & 63;
    if (lane == 0) { rs[wid] = s; rq[wid] = q; }
    __syncthreads();
    if (tid == 0) {
        float S = rs[0] + rs[1] + rs[2] + rs[3];
        float Q = rq[0] + rq[1] + rq[2] + rq[3];
        const float invN = 1.0f / (float)(kCg * kT);
        float mean = S * invN;
        float var  = Q * invN - mean * mean;
        stats[bg * 2 + 0] = mean;
        stats[bg * 2 + 1] = rsqrtf(var + kEps);
    }
}

// ---------------------------------------------------------------------------
// Kernel 2: apply GroupNorm affine + transpose -> normT[b][t][c] bf16.
// ---------------------------------------------------------------------------
__global__ __launch_bounds__(256) void gn_apply_t_kernel(const float* __restrict__ x,
                                                         const float* __restrict__ stats,
                                                         const float* __restrict__ w,
                                                         const float* __restrict__ bias,
                                                         unsigned short* __restrict__ normT) {
    __shared__ float Ls[64][65];
    int t0 = blockIdx.x * 64;
    int c0 = blockIdx.y * 64;
    int b  = blockIdx.z;
    int tid = threadIdx.x;
    #pragma unroll
    for (int p = 0; p < 4; ++p) {
        int idx = tid + p * 256;
        int cl = idx >> 4, t4 = idx & 15;
        int c = c0 + cl;
        int bg = b * kG + (c >> 4);
        float mean = stats[bg * 2 + 0];
        float rstd = stats[bg * 2 + 1];
        float sw = w[c] * rstd;
        float sb = bias[c] - mean * sw;
        float4 v = *(const float4*)&x[((size_t)b * kC + c) * kT + t0 + t4 * 4];
        Ls[t4 * 4 + 0][cl] = v.x * sw + sb;
        Ls[t4 * 4 + 1][cl] = v.y * sw + sb;
        Ls[t4 * 4 + 2][cl] = v.z * sw + sb;
        Ls[t4 * 4 + 3][cl] = v.w * sw + sb;
    }
    __syncthreads();
    {
        int row = tid >> 2, cq = (tid & 3) * 16;
        unsigned tmp[8];
        #pragma unroll
        for (int i = 0; i < 8; ++i)
            tmp[i] = pk2bf(Ls[row][cq + 2 * i], Ls[row][cq + 2 * i + 1]);
        uint4* dst = (uint4*)&normT[((size_t)b * kT + t0 + row) * kC + c0 + cq];
        dst[0] = make_uint4(tmp[0], tmp[1], tmp[2], tmp[3]);
        dst[1] = make_uint4(tmp[4], tmp[5], tmp[6], tmp[7]);
    }
}

// ---------------------------------------------------------------------------
// Kernel 3: qkv GEMM (bf16 MFMA), R9 structure. Epilogue writes q/k/v in
// PRE-FRAGMENTED MFMA operand layouts:
//   q/k: frag[tb=t/32][ks=c/16][hi=(c/8)&1][ln=t&31][e=c&7]
//   v:   frag[sg=s/16][hi=(s/8)&1][c][e=s&7]
// ---------------------------------------------------------------------------
__global__ __launch_bounds__(256) void qkv_gemm_kernel(const unsigned short* __restrict__ wbf,
                                                       const float* __restrict__ qkv_b,
                                                       const unsigned short* __restrict__ normT,
                                                       unsigned short* __restrict__ qTg,
                                                       unsigned short* __restrict__ kTg,
                                                       unsigned short* __restrict__ vCg) {
    constexpr int LDK = 72;
    constexpr int LDV = 136;   // v-staging row length (bf16), 272 B, 16B-aligned
    __shared__ __align__(16) unsigned short As[64 * LDK];
    __shared__ __align__(16) unsigned short Bs[128 * LDK];   // also epilogue staging

    int t0 = blockIdx.x * 128;
    int m0 = blockIdx.y * 64;
    int b  = blockIdx.z;
    const unsigned short* Ab = wbf + (size_t)m0 * kC;
    const unsigned short* Bb = normT + (size_t)b * kT * kC;

    int tid = threadIdx.x;
    int wave = tid >> 6, lane = tid & 63;
    int ln15 = lane & 15, quad = lane >> 4;
    int wm = wave >> 1, wt = wave & 1;

    f32x4 acc[2][4] = {};

    for (int k0 = 0; k0 < kC; k0 += 64) {
        __syncthreads();
        #pragma unroll
        for (int p = 0; p < 2; ++p) {
            int idx = tid + p * 256;
            int row = idx >> 3, seg = idx & 7;
            *(uint4*)&As[row * LDK + seg * 8] =
                *(const uint4*)&Ab[(size_t)row * kC + k0 + seg * 8];
        }
        #pragma unroll
        for (int p = 0; p < 4; ++p) {
            int idx = tid + p * 256;
            int row = idx >> 3, seg = idx & 7;
            *(uint4*)&Bs[row * LDK + seg * 8] =
                *(const uint4*)&Bb[(size_t)(t0 + row) * kC + k0 + seg * 8];
        }
        __syncthreads();
        #pragma unroll
        for (int ks = 0; ks < 2; ++ks) {
            bf16x8 af[2], bf[4];
            #pragma unroll
            for (int i = 0; i < 2; ++i)
                af[i] = *(bf16x8*)&As[(wm * 32 + i * 16 + ln15) * LDK + ks * 32 + quad * 8];
            #pragma unroll
            for (int j = 0; j < 4; ++j)
                bf[j] = *(bf16x8*)&Bs[(wt * 64 + j * 16 + ln15) * LDK + ks * 32 + quad * 8];
            #pragma unroll
            for (int i = 0; i < 2; ++i)
                #pragma unroll
                for (int j = 0; j < 4; ++j)
                    acc[i][j] = __builtin_amdgcn_mfma_f32_16x16x32_bf16(
                        af[i], bf[j], acc[i][j], 0, 0, 0);
        }
    }

    int type = (m0 % 192) / 64;   // 0=q, 1=k, 2=v
    int h = m0 / 192;
    int bh = b * kH + h;
    __syncthreads();   // all MFMA reads of Bs done; reuse Bs as staging
    #pragma unroll
    for (int i = 0; i < 2; ++i) {
        float4 bv = *(const float4*)&qkv_b[m0 + wm * 32 + i * 16 + quad * 4];
        const float* bp = (const float*)&bv;
        #pragma unroll
        for (int j = 0; j < 4; ++j) {
            int tl = wt * 64 + j * 16 + ln15;
            int c = wm * 32 + i * 16 + quad * 4;
            float v0 = acc[i][j][0] + bp[0];
            float v1 = acc[i][j][1] + bp[1];
            float v2 = acc[i][j][2] + bp[2];
            float v3 = acc[i][j][3] + bp[3];
            if (type == 0) {
                v0 *= kQScale; v1 *= kQScale; v2 *= kQScale; v3 *= kQScale;
            }
            if (type != 2) {
                *(uint2*)&Bs[tl * LDK + c] = make_uint2(pk2bf(v0, v1), pk2bf(v2, v3));
            } else {
                Bs[(c + 0) * LDV + tl] = f2bf(v0);
                Bs[(c + 1) * LDV + tl] = f2bf(v1);
                Bs[(c + 2) * LDV + tl] = f2bf(v2);
                Bs[(c + 3) * LDV + tl] = f2bf(v3);
            }
        }
    }
    __syncthreads();
    if (type != 2) {
        unsigned short* base = ((type == 0) ? qTg : kTg) + (size_t)bh * (kT * kCh);
        #pragma unroll
        for (int p = 0; p < 4; ++p) {
            int f = tid + p * 256;
            int ln = f & 31, hif = (f >> 5) & 1, ks = (f >> 6) & 3, tb = f >> 8;
            *(uint4*)&base[((t0 >> 5) + tb) * 2048 + ks * 512 + hif * 256 + ln * 8] =
                *(uint4*)&Bs[(tb * 32 + ln) * LDK + ks * 16 + hif * 8];
        }
    } else {
        unsigned short* base = vCg + (size_t)bh * (kT * kCh);
        #pragma unroll
        for (int p = 0; p < 4; ++p) {
            int f = tid + p * 256;
            int c = f & 63, hif = (f >> 6) & 1, sg = f >> 7;
            *(uint4*)&base[((t0 >> 4) + sg) * 1024 + hif * 512 + c * 8] =
                *(uint4*)&Bs[c * LDV + sg * 16 + hif * 8];
        }
    }
}

// ---------------------------------------------------------------------------
// Kernel 4: BARRIER-FREE MFMA flash attention, 32x32x16, no-max exp2.
// Wave owns a 32-t chunk and computes S for ALL s, so P never crosses
// waves; the C-layout -> B-operand transform goes through a PER-WAVE
// private LDS region. R12's NaN root cause: the P-store (uint2*) and
// P-load (short-vector*) had distinct TBAA types, licensing the compiler
// to reorder the ds_read above the ds_write (no barrier = no fence).
// Fix: P buffer is uniformly unsigned-int typed for BOTH store and load,
// plus explicit compiler memory fences around the store->load boundary
// and at the loop backedge. Hardware DS ops are in-order per wave.
// C-layout: col t=lane&31, row s=(reg&3)+8*(reg>>2)+4*hi (m74/m101).
// ---------------------------------------------------------------------------
__global__ __launch_bounds__(256, 2) void attn_mfma_kernel(const unsigned short* __restrict__ qTg,
                                                           const unsigned short* __restrict__ kTg,
                                                           const unsigned short* __restrict__ vCg,
                                                           unsigned short* __restrict__ attnT) {
    constexpr int LDPu = 36;   // P row length in uints: 32 (64 bf16) + 4 pad
    __shared__ __align__(16) unsigned int Ps[4][32 * LDPu];   // per-wave regions

    int bh = blockIdx.y;
    int t0 = blockIdx.x * 128;
    int b = bh >> 2, h = bh & 3;

    int tid = threadIdx.x;
    int wave = tid >> 6, lane = tid & 63;
    int ln31 = lane & 31, hi = lane >> 5;
    unsigned int* Pw = &Ps[wave][0];

    const unsigned short* qb = qTg + (size_t)bh * (kT * kCh);
    const unsigned short* kb = kTg + (size_t)bh * (kT * kCh);
    const unsigned short* vb = vCg + (size_t)bh * (kT * kCh);

    // Q fragments (loop-invariant), wave's t-chunk = t0 + wave*32
    bf16x8 qf[4];
    {
        const unsigned short* qp = qb + ((t0 >> 5) + wave) * 2048 + hi * 256 + ln31 * 8;
        #pragma unroll
        for (int ks = 0; ks < 4; ++ks) qf[ks] = *(const bf16x8*)(qp + ks * 512);
    }
    // K fragments: kf[st*4+ks] = K[s = st*32+ln31][c-slice ks]; +4096/iter
    const unsigned short* kptr = kb + hi * 256 + ln31 * 8;
    // V fragments: vf[ct*4+ks2] = V[c = ct*32+ln31][s-slice ks2]; +4096/iter
    const unsigned short* vptr = vb + hi * 512 + ln31 * 8;

    bf16x8 kf[8], vf[8];
    #pragma unroll
    for (int i = 0; i < 8; ++i)
        kf[i] = *(const bf16x8*)(kptr + (i >> 2) * 2048 + (i & 3) * 512);
    #pragma unroll
    for (int i = 0; i < 8; ++i)
        vf[i] = *(const bf16x8*)(vptr + (i & 3) * 1024 + (i >> 2) * 256);

    float l_r = 0.f;
    f32x16 accO0 = {}, accO1 = {};
    union PunP { uint4 u; bf16x8 f; };

    for (int s0 = 0; s0 < kT; s0 += 64) {
        // ---- S^T: 2 s-tiles of 32 x wave's 32 t (8 MFMAs)
        f32x16 accS0 = {}, accS1 = {};
        #pragma unroll
        for (int ks = 0; ks < 4; ++ks)
            accS0 = __builtin_amdgcn_mfma_f32_32x32x16_bf16(kf[ks], qf[ks], accS0, 0, 0, 0);
        #pragma unroll
        for (int ks = 0; ks < 4; ++ks)
            accS1 = __builtin_amdgcn_mfma_f32_32x32x16_bf16(kf[4 + ks], qf[ks], accS1, 0, 0, 0);

        // prefetch next K fragments
        if (s0 + 64 < kT) {
            kptr += 4096;
            #pragma unroll
            for (int i = 0; i < 8; ++i)
                kf[i] = *(const bf16x8*)(kptr + (i >> 2) * 2048 + (i & 3) * 512);
        }

        // ---- softmax: p = exp2(S); store to wave-private LDS as uints
        // (reg 4g+j of tile st -> s = st*32+8g+4hi+j; uint idx = s/2)
        float rs = 0.f;
        #pragma unroll
        for (int g = 0; g < 4; ++g) {
            float p0 = __builtin_amdgcn_exp2f(accS0[4 * g + 0]);
            float p1 = __builtin_amdgcn_exp2f(accS0[4 * g + 1]);
            float p2 = __builtin_amdgcn_exp2f(accS0[4 * g + 2]);
            float p3 = __builtin_amdgcn_exp2f(accS0[4 * g + 3]);
            rs += (p0 + p1) + (p2 + p3);
            int ui = ln31 * LDPu + 4 * g + 2 * hi;
            Pw[ui + 0] = pk2bf_trunc(p0, p1);
            Pw[ui + 1] = pk2bf_trunc(p2, p3);
        }
        #pragma unroll
        for (int g = 0; g < 4; ++g) {
            float p0 = __builtin_amdgcn_exp2f(accS1[4 * g + 0]);
            float p1 = __builtin_amdgcn_exp2f(accS1[4 * g + 1]);
            float p2 = __builtin_amdgcn_exp2f(accS1[4 * g + 2]);
            float p3 = __builtin_amdgcn_exp2f(accS1[4 * g + 3]);
            rs += (p0 + p1) + (p2 + p3);
            int ui = ln31 * LDPu + 16 + 4 * g + 2 * hi;
            Pw[ui + 0] = pk2bf_trunc(p0, p1);
            Pw[ui + 1] = pk2bf_trunc(p2, p3);
        }
        rs += __shfl_xor(rs, 32);
        l_r += rs;
        __asm__ __volatile__("" ::: "memory");   // fence: stores before loads

        // ---- O^T: accO[ct] += V * P (8 MFMAs); pf = uint4 load, bitcast
        #pragma unroll
        for (int i = 0; i < 4; ++i) {
            PunP pk;
            pk.u = *(const uint4*)&Pw[ln31 * LDPu + i * 8 + hi * 4];
            accO0 = __builtin_amdgcn_mfma_f32_32x32x16_bf16(vf[i],     pk.f, accO0, 0, 0, 0);
            accO1 = __builtin_amdgcn_mfma_f32_32x32x16_bf16(vf[4 + i], pk.f, accO1, 0, 0, 0);
        }

        // prefetch next V fragments
        if (s0 + 64 < kT) {
            vptr += 4096;
            #pragma unroll
            for (int i = 0; i < 8; ++i)
                vf[i] = *(const bf16x8*)(vptr + (i & 3) * 1024 + (i >> 2) * 256);
        }
        __asm__ __volatile__("" ::: "memory");   // fence: loads before next stores
    }

    // ---- finalize: l fully lane-resident (both hi halves hold full sum)
    float linv = 1.0f / l_r;
    int t = t0 + wave * 32 + ln31;
    #pragma unroll
    for (int ct = 0; ct < 2; ++ct) {
        const f32x16& ao = ct ? accO1 : accO0;
        #pragma unroll
        for (int g = 0; g < 4; ++g) {
            int c = h * kCh + ct * 32 + 8 * g + 4 * hi;
            float v0 = ao[4 * g + 0] * linv;
            float v1 = ao[4 * g + 1] * linv;
            float v2 = ao[4 * g + 2] * linv;
            float v3 = ao[4 * g + 3] * linv;
            *(uint2*)&attnT[((size_t)b * kT + t) * kC + c] =
                make_uint2(pk2bf(v0, v1), pk2bf(v2, v3));
        }
    }
}

// ---------------------------------------------------------------------------
// Kernel 5: proj GEMM (bf16 MFMA, R9 structure) + bias + residual -> fp32.
// ---------------------------------------------------------------------------
__global__ __launch_bounds__(256) void proj_gemm_kernel(const unsigned short* __restrict__ wpbf,
                                                        const float* __restrict__ proj_b,
                                                        const unsigned short* __restrict__ attnT,
                                                        const float* __restrict__ x,
                                                        float* __restrict__ out) {
    constexpr int LDK = 72;
    __shared__ __align__(16) unsigned short As[64 * LDK];
    __shared__ __align__(16) unsigned short Bs[128 * LDK];

    int t0 = blockIdx.x * 128;
    int m0 = blockIdx.y * 64;
    int b  = blockIdx.z;
    const unsigned short* Ab = wpbf + (size_t)m0 * kC;
    const unsigned short* Bb = attnT + (size_t)b * kT * kC;

    int tid = threadIdx.x;
    int wave = tid >> 6, lane = tid & 63;
    int ln15 = lane & 15, quad = lane >> 4;
    int wm = wave >> 1, wt = wave & 1;

    f32x4 acc[2][4] = {};

    for (int k0 = 0; k0 < kC; k0 += 64) {
        __syncthreads();
        #pragma unroll
        for (int p = 0; p < 2; ++p) {
            int idx = tid + p * 256;
            int row = idx >> 3, seg = idx & 7;
            *(uint4*)&As[row * LDK + seg * 8] =
                *(const uint4*)&Ab[(size_t)row * kC + k0 + seg * 8];
        }
        #pragma unroll
        for (int p = 0; p < 4; ++p) {
            int idx = tid + p * 256;
            int row = idx >> 3, seg = idx & 7;
            *(uint4*)&Bs[row * LDK + seg * 8] =
                *(const uint4*)&Bb[(size_t)(t0 + row) * kC + k0 + seg * 8];
        }
        __syncthreads();
        #pragma unroll
        for (int ks = 0; ks < 2; ++ks) {
            bf16x8 af[2], bf[4];
            #pragma unroll
            for (int i = 0; i < 2; ++i)
                af[i] = *(bf16x8*)&As[(wm * 32 + i * 16 + ln15) * LDK + ks * 32 + quad * 8];
            #pragma unroll
            for (int j = 0; j < 4; ++j)
                bf[j] = *(bf16x8*)&Bs[(wt * 64 + j * 16 + ln15) * LDK + ks * 32 + quad * 8];
            #pragma unroll
            for (int i = 0; i < 2; ++i)
                #pragma unroll
                for (int j = 0; j < 4; ++j)
                    acc[i][j] = __builtin_amdgcn_mfma_f32_16x16x32_bf16(
                        af[i], bf[j], acc[i][j], 0, 0, 0);
        }
    }

    #pragma unroll
    for (int i = 0; i < 2; ++i) {
        float4 bv = *(const float4*)&proj_b[m0 + wm * 32 + i * 16 + quad * 4];
        const float* bp = (const float*)&bv;
        #pragma unroll
        for (int j = 0; j < 4; ++j) {
            int t = t0 + wt * 64 + j * 16 + ln15;
            int mbase = m0 + wm * 32 + i * 16 + quad * 4;
            #pragma unroll
            for (int r = 0; r < 4; ++r) {
                size_t off = ((size_t)b * kC + mbase + r) * kT + t;
                out[off] = acc[i][j][r] + bp[r] + x[off];
            }
        }
    }
}

// ---------------------------------------------------------------------------
extern "C" void kernel_launch(void* const* d_in, const int* in_sizes, int n_in,
                              void* d_out, int out_size, void* d_ws, size_t ws_size,
                              hipStream_t stream) {
    const float* x      = (const float*)d_in[0];
    const float* norm_w = (const float*)d_in[1];
    const float* norm_b = (const float*)d_in[2];
    const float* qkv_w  = (const float*)d_in[3];
    const float* qkv_b  = (const float*)d_in[4];
    const float* proj_w = (const float*)d_in[5];
    const float* proj_b = (const float*)d_in[6];
    float* out = (float*)d_out;

    // Workspace: stats fp32[128] | bf16: normT[4.19M] wbf[262144] qT kT vC attnT[4.19M each]
    float* stats = (float*)d_ws;
    unsigned short* wsbf  = (unsigned short*)((float*)d_ws + 128);
    unsigned short* normT = wsbf;
    unsigned short* wbf   = normT + (size_t)kB * kT * kC;
    unsigned short* qTp   = wbf + 262144;
    unsigned short* kTp   = qTp + (size_t)kB * kH * kT * kCh;
    unsigned short* vCp   = kTp + (size_t)kB * kH * kT * kCh;
    unsigned short* attnT = vCp + (size_t)kB * kH * kT * kCh;
    unsigned short* wpbf  = wbf + 196608;

    prep_kernel<<<192, 256, 0, stream>>>(x, stats, qkv_w, proj_w, wbf);
    gn_apply_t_kernel<<<dim3(kT / 64, kC / 64, kB), 256, 0, stream>>>(
        x, stats, norm_w, norm_b, normT);
    qkv_gemm_kernel<<<dim3(kT / 128, 12, kB), 256, 0, stream>>>(
        wbf, qkv_b, normT, qTp, kTp, vCp);
    attn_mfma_kernel<<<dim3(kT / 128, kB * kH), 256, 0, stream>>>(qTp, kTp, vCp, attnT);
    proj_gemm_kernel<<<dim3(kT / 128, kC / 64, kB), 256, 0, stream>>>(
        wpbf, proj_b, attnT, x, out);
}